// Round 15
// baseline (95.787 us; speedup 1.0000x reference)
//
#include <hip/hip_runtime.h>
#include <stdint.h>

constexpr int B = 2, H = 256, W = 256, G = 96, C = 12, K = 128;
constexpr int HW = H * W;          // 65536
constexpr int G3 = G * G * G;      // 884736
constexpr float CENTER_THRESHOLD = 0.1f;
constexpr int STUFF_AREA = 2048;
constexpr int LABEL_DIVISOR = 1000;
constexpr float VOXEL_SIZE = 0.0625f;
constexpr float TRUNCATION = 3.0f;
constexpr float TSDF_THRESH = 1.5f;
constexpr float DEPTH_MAX = 6.0f;
constexpr float HALF_EXT = 3.0f;   // G*VOXEL_SIZE/2
constexpr int TOPK_CAP = 2048;     // LDS candidate capacity (16 KB; n~1340)
constexpr int TOPK_NB = 64;        // blocks per batch for k_topk
constexpr int PAN2_BLOCKS = (B * HW) / 1024;   // 128
constexpr int F3D_BLOCKS = (B * G3) / 512;     // 3456 (2 voxels/thread)
constexpr int F3D_STUFFB = (B * G3) / 4096;    // 432 (k_stuff)

// output layout (floats)
constexpr size_t O_PAN2 = 0;
constexpr size_t O_PAN3 = 131072;
constexpr size_t O_GEOM = 1900544;
constexpr size_t O_CENT = 3670016;
constexpr size_t O_CLS  = 3670528;
constexpr size_t O_SCR  = 3670784;

// ws layout (bytes)
constexpr size_t WS_SC   = 2304;
constexpr size_t WS_CL   = 3328;
constexpr size_t WS_SEM2 = 4352;
constexpr size_t WS_NMS  = 135424;
constexpr size_t WS_CV   = 266496;
constexpr size_t WS_CI   = 790784;
constexpr size_t WS_STUF = 1315072;   // B*G3 bytes (stuff candidate map)
constexpr size_t WS_CYV  = 3084544;
constexpr size_t WS_CXV  = 3085568;

typedef float f32x2 __attribute__((ext_vector_type(2)));

// VOP3P packed fp32: elementwise IEEE-identical to scalar v_add/v_mul.
__device__ inline f32x2 pk_add(f32x2 a, f32x2 b) {
    f32x2 d;
    asm("v_pk_add_f32 %0, %1, %2" : "=v"(d) : "v"(a), "v"(b));
    return d;
}
__device__ inline f32x2 pk_mul(f32x2 a, f32x2 b) {
    f32x2 d;
    asm("v_pk_mul_f32 %0, %1, %2" : "=v"(d) : "v"(a), "v"(b));
    return d;
}

// 4 rows per block, 4 pixels per thread. Separable clamped 7x7 max.
// Candidate emission is block-compacted: LDS staging + ONE global atomic
// per block (R12 win: −16 us vs per-candidate global atomics).
__global__ __launch_bounds__(256)
void k_pre2d(const float* __restrict__ sem2in,
             const float* __restrict__ center2d,
             uint8_t* __restrict__ semMap, uint8_t* __restrict__ nmsMask,
             float* __restrict__ candVal, int* __restrict__ candIdx,
             int* __restrict__ candCount, int* __restrict__ counts2d) {
    __shared__ float vm[4][W];
    __shared__ float lcv[1024];
    __shared__ int   lci[1024];
    __shared__ int lcnt[4];
    __shared__ int cCount;
    __shared__ int gBase;
    int t = threadIdx.x;
    int r = t >> 6;                    // row within block (wave-uniform)
    int c0 = (t & 63) * 4;
    int b = blockIdx.x / (H / 4);
    int h = (blockIdx.x % (H / 4)) * 4 + r;
    if (t < 4) lcnt[t] = 0;
    if (t == 0) cCount = 0;
    const float* hmb = center2d + (size_t)b * HW;
    int h0 = max(h - 3, 0), h1 = min(h + 3, H - 1);
    float4 hm4 = *(const float4*)(hmb + h * W + c0);
    float m0 = -INFINITY, m1 = -INFINITY, m2 = -INFINITY, m3 = -INFINITY;
    for (int y = h0; y <= h1; ++y) {
        float4 v = *(const float4*)(hmb + y * W + c0);
        m0 = fmaxf(m0, v.x); m1 = fmaxf(m1, v.y);
        m2 = fmaxf(m2, v.z); m3 = fmaxf(m3, v.w);
    }
    *(float4*)&vm[r][c0] = make_float4(m0, m1, m2, m3);
    __syncthreads();
    float mm[4];
#pragma unroll
    for (int q = 0; q < 4; ++q) {
        int c = c0 + q;
        int w0 = max(c - 3, 0), w1 = min(c + 3, W - 1);
        float mx = -INFINITY;
        for (int x = w0; x <= w1; ++x) mx = fmaxf(mx, vm[r][x]);
        mm[q] = mx;
    }
    // semantic argmax (first max wins)
    const float* s = sem2in + (size_t)b * C * HW + h * W + c0;
    float4 s0 = *(const float4*)s;
    float bv[4] = {s0.x, s0.y, s0.z, s0.w};
    int cls[4] = {0, 0, 0, 0};
#pragma unroll 4
    for (int c = 1; c < C; ++c) {
        float4 x = *(const float4*)(s + (size_t)c * HW);
        float xa[4] = {x.x, x.y, x.z, x.w};
#pragma unroll
        for (int q = 0; q < 4; ++q)
            if (xa[q] > bv[q]) { bv[q] = xa[q]; cls[q] = c; }
    }
    int p = h * W + c0;
    int gid = b * HW + p;
    *(uchar4*)(semMap + gid) =
        make_uchar4((uint8_t)cls[0], (uint8_t)cls[1], (uint8_t)cls[2], (uint8_t)cls[3]);
    float hma[4] = {hm4.x, hm4.y, hm4.z, hm4.w};
#pragma unroll
    for (int q = 0; q < 4; ++q) {
        if (cls[q] >= 8) atomicAdd(&lcnt[cls[q] - 8], 1);
        bool cand = (hma[q] == mm[q]);
        nmsMask[gid + q] = cand ? 1 : 0;
        if (cand) {
            int pos = atomicAdd(&cCount, 1);   // LDS atomic: cheap
            lcv[pos] = hma[q];
            lci[pos] = p + q;
        }
    }
    __syncthreads();
    if (t == 0) gBase = atomicAdd(&candCount[b], cCount);  // ONE global atomic
    if (t < 4) atomicAdd(&counts2d[b * C + 8 + t], lcnt[t]);
    __syncthreads();
    // coalesced copy-out of the block's candidates
    for (int i = t; i < cCount; i += 256) {
        int pos = gBase + i;
        if (pos < HW) {
            candVal[(size_t)b * HW + pos] = lcv[i];
            candIdx[(size_t)b * HW + pos] = lci[i];
        }
    }
}

// Wave-per-candidate exact top-k (rank scatter; order-invariant).
__global__ __launch_bounds__(256)
void k_topk(const uint8_t* __restrict__ semMap, const uint8_t* __restrict__ nmsMask,
            const float* __restrict__ candVal, const int* __restrict__ candIdx,
            const int* __restrict__ candCount,
            float* __restrict__ scA, int* __restrict__ clA,
            float* __restrict__ cyV, float* __restrict__ cxV,
            float* __restrict__ out) {
    __shared__ float2 cd[TOPK_CAP];
    int b = blockIdx.x / TOPK_NB;
    int sub = blockIdx.x % TOPK_NB;
    int t = threadIdx.x;
    int lane = t & 63;
    int wv = sub * 4 + (t >> 6);
    int n = candCount[b];
    if (n > HW) n = HW;
    const float* cv = candVal + (size_t)b * HW;
    const int*  ci = candIdx + (size_t)b * HW;
    bool useLds = (n <= TOPK_CAP);
    if (useLds) {
        for (int i = t; i < n; i += 256)
            cd[i] = make_float2(cv[i], __int_as_float(ci[i]));
    }
    __syncthreads();
    for (int i = wv; i < n; i += TOPK_NB * 4) {
        float v; int id;
        if (useLds) { float2 c = cd[i]; v = c.x; id = __float_as_int(c.y); }
        else        { v = cv[i]; id = ci[i]; }
        int r = 0;
        if (useLds) {
            for (int j = lane; j < n; j += 64) {
                float2 c = cd[j];
                r += (c.x > v) || (c.x == v && __float_as_int(c.y) < id);
            }
        } else {
            for (int j = lane; j < n; j += 64) {
                float vj = cv[j]; int ij = ci[j];
                r += (vj > v) || (vj == v && ij < id);
            }
        }
#pragma unroll
        for (int off = 32; off >= 1; off >>= 1) r += __shfl_xor(r, off, 64);
        if (lane == 0 && r < K) {
            int o = b * K + r;
            float fy = (float)(id / W);
            float fx = (float)(id % W);
            int cls = (int)semMap[(size_t)b * HW + id];
            bool val = v > CENTER_THRESHOLD;
            scA[o] = v; clA[o] = cls;
            cyV[o] = val ? fy : INFINITY;
            cxV[o] = val ? fx : INFINITY;
            out[O_CENT + (size_t)o * 2 + 0] = fy;
            out[O_CENT + (size_t)o * 2 + 1] = fx;
            out[O_CLS + o] = (float)cls;
            out[O_SCR + o] = v;
        }
    }
    if (sub == 0 && t == 0 && n < K) {
        int r = n;
        for (int p = 0; p < HW && r < K; ++p) {
            if (!nmsMask[(size_t)b * HW + p]) {
                int o = b * K + r;
                float fy = (float)(p / W);
                float fx = (float)(p % W);
                int cls = (int)semMap[(size_t)b * HW + p];
                scA[o] = 0.0f; clA[o] = cls;
                cyV[o] = INFINITY;
                cxV[o] = INFINITY;
                out[O_CENT + (size_t)o * 2 + 0] = fy;
                out[O_CENT + (size_t)o * 2 + 1] = fx;
                out[O_CLS + o] = (float)cls;
                out[O_SCR + o] = 0.0f;
                ++r;
            }
        }
    }
}

// Exact group-min argmin over 128 centers for 4 points held as 2 f32x2 pairs.
// (pan2d branch). Same semantics as ever: pass-1 full-unroll 8x16 min
// chains; strict-< merge; reverse rescan -> first-k-wins. Bit-exact.
__device__ __forceinline__ void argmin128(const float4* __restrict__ cc4,
                                          const float2* __restrict__ cc2,
                                          const f32x2 vv2[2], const f32x2 uu2[2],
                                          int bi[4]) {
#pragma clang fp contract(off)
    f32x2 m0 = {INFINITY, INFINITY}, m1 = {INFINITY, INFINITY};
    int gs[4] = {0, 0, 0, 0};
    for (int g = 0; g < 8; ++g) {
        f32x2 b0 = {INFINITY, INFINITY}, b1 = {INFINITY, INFINITY};
#pragma unroll
        for (int kk = 0; kk < 16; ++kk) {
            float4 c4 = cc4[(g << 4) + kk];
            f32x2 ncy; ncy[0] = c4.x; ncy[1] = c4.y;
            f32x2 ncx; ncx[0] = c4.z; ncx[1] = c4.w;
            f32x2 dv = pk_add(vv2[0], ncy);
            f32x2 du = pk_add(uu2[0], ncx);
            f32x2 d0 = pk_add(pk_mul(dv, dv), pk_mul(du, du));
            dv = pk_add(vv2[1], ncy);
            du = pk_add(uu2[1], ncx);
            f32x2 d1 = pk_add(pk_mul(dv, dv), pk_mul(du, du));
            b0[0] = fminf(b0[0], d0[0]); b0[1] = fminf(b0[1], d0[1]);
            b1[0] = fminf(b1[0], d1[0]); b1[1] = fminf(b1[1], d1[1]);
        }
        if (b0[0] < m0[0]) { m0[0] = b0[0]; gs[0] = g; }
        if (b0[1] < m0[1]) { m0[1] = b0[1]; gs[1] = g; }
        if (b1[0] < m1[0]) { m1[0] = b1[0]; gs[2] = g; }
        if (b1[1] < m1[1]) { m1[1] = b1[1]; gs[3] = g; }
    }
    float vq[4] = {vv2[0][0], vv2[0][1], vv2[1][0], vv2[1][1]};
    float uq[4] = {uu2[0][0], uu2[0][1], uu2[1][0], uu2[1][1]};
    float mq[4] = {m0[0], m0[1], m1[0], m1[1]};
#pragma unroll
    for (int q = 0; q < 4; ++q) {
        int kb = 0;
        int gbase = gs[q] << 4;
#pragma unroll
        for (int kk = 15; kk >= 0; --kk) {
            float2 c2 = cc2[gbase + kk];
            float dv = vq[q] + c2.x;
            float du = uq[q] + c2.y;
            float d = dv * dv + du * du;
            if (d == mq[q]) kb = kk;        // last write = smallest kk
        }
        bi[q] = gbase + kb;
    }
}

// Same argmin for ONE f32x2 point-pair (3D branch, 2 voxels/thread).
__device__ __forceinline__ void argmin128_p2(const float4* __restrict__ cc4,
                                             const float2* __restrict__ cc2,
                                             f32x2 vv, f32x2 uu, int bi[2]) {
#pragma clang fp contract(off)
    f32x2 m = {INFINITY, INFINITY};
    int gs[2] = {0, 0};
    for (int g = 0; g < 8; ++g) {
        f32x2 bm = {INFINITY, INFINITY};
#pragma unroll
        for (int kk = 0; kk < 16; ++kk) {
            float4 c4 = cc4[(g << 4) + kk];
            f32x2 ncy; ncy[0] = c4.x; ncy[1] = c4.y;
            f32x2 ncx; ncx[0] = c4.z; ncx[1] = c4.w;
            f32x2 dv = pk_add(vv, ncy);
            f32x2 du = pk_add(uu, ncx);
            f32x2 d  = pk_add(pk_mul(dv, dv), pk_mul(du, du));
            bm[0] = fminf(bm[0], d[0]);
            bm[1] = fminf(bm[1], d[1]);
        }
        if (bm[0] < m[0]) { m[0] = bm[0]; gs[0] = g; }
        if (bm[1] < m[1]) { m[1] = bm[1]; gs[1] = g; }
    }
    float vq[2] = {vv[0], vv[1]};
    float uq[2] = {uu[0], uu[1]};
    float mq[2] = {m[0], m[1]};
#pragma unroll
    for (int q = 0; q < 2; ++q) {
        int kb = 0;
        int gbase = gs[q] << 4;
#pragma unroll
        for (int kk = 15; kk >= 0; --kk) {
            float2 c2 = cc2[gbase + kk];
            float dv = vq[q] + c2.x;
            float du = uq[q] + c2.y;
            float d = dv * dv + du * du;
            if (d == mq[q]) kb = kk;        // last write = smallest kk
        }
        bi[q] = gbase + kb;
    }
}

// Fused: pan2d blocks [0,PAN2_BLOCKS) + {geom3d+pan3d} blocks (rest).
// R14 experiment: 3D branch at 2 voxels/thread (double TLP, same total
// VALU work) — attacks the 49%-VALUBusy / 25%-occupancy latency signature.
// Plain launch_bounds(256): (256,N) caps VGPR at ~256/N on this toolchain;
// capping below need spills (R7/R9 lessons).
__global__ __launch_bounds__(256)
void k_fuse(const float* __restrict__ geom, const float* __restrict__ occ,
            const float* __restrict__ sem3in,
            uint8_t* __restrict__ stuffCand, int* __restrict__ counts3d,
            const float* __restrict__ offset2d,
            const uint8_t* __restrict__ semMap,
            const int* __restrict__ counts2d,
            const float* __restrict__ off3,
            const float* __restrict__ intr,
            const float* __restrict__ scA, const int* __restrict__ clA,
            const float* __restrict__ cyV, const float* __restrict__ cxV,
            float* __restrict__ out) {
#pragma clang fp contract(off)
    __shared__ float4 cc4[K];
    __shared__ float2 cc2[K];
    __shared__ int clsL[K];
    __shared__ int lcnt[C];
    __shared__ int cntL[C];
    int t = threadIdx.x;
    if (blockIdx.x < PAN2_BLOCKS) {
        // ---- pan2d: 4 pixels/thread (unchanged) ----
        int b = blockIdx.x / (PAN2_BLOCKS / B);          // uniform
        int base = blockIdx.x * 1024 + t * 4;
        int p = base - b * HW;
        if (t < K) {
            float cy = cyV[b * K + t], cx = cxV[b * K + t];
            cc4[t] = make_float4(-cy, -cy, -cx, -cx);
            cc2[t] = make_float2(-cy, -cx);
            clsL[t] = clA[b * K + t];
        }
        if (t < C) cntL[t] = counts2d[b * C + t];
        __syncthreads();
        bool anyV = scA[b * K] > CENTER_THRESHOLD;       // uniform
        int h = p / W, w = p % W;
        const float* offb = offset2d + (size_t)b * 2 * HW + p;
        float4 oy = *(const float4*)offb;
        float4 ox = *(const float4*)(offb + HW);
        f32x2 py2[2], px2[2];
        py2[0][0] = (float)h + oy.x;        py2[0][1] = (float)h + oy.y;
        py2[1][0] = (float)h + oy.z;        py2[1][1] = (float)h + oy.w;
        px2[0][0] = (float)(w + 0) + ox.x;  px2[0][1] = (float)(w + 1) + ox.y;
        px2[1][0] = (float)(w + 2) + ox.z;  px2[1][1] = (float)(w + 3) + ox.w;
        int bi[4];
        argmin128(cc4, cc2, py2, px2, bi);
        uchar4 s4 = *(const uchar4*)(semMap + base);
        int sa[4] = {s4.x, s4.y, s4.z, s4.w};
        float pout[4];
#pragma unroll
        for (int q = 0; q < 4; ++q) {
            int sem = sa[q];
            int pan;
            if (sem >= 1 && sem <= 7) {
                pan = anyV ? (clsL[bi[q]] * LABEL_DIVISOR + bi[q] + 1) : 0;
            } else {
                pan = (cntL[sem] >= STUFF_AREA) ? sem * LABEL_DIVISOR : 0;
            }
            pout[q] = (float)pan;
        }
        *(float4*)(out + O_PAN2 + base) = make_float4(pout[0], pout[1], pout[2], pout[3]);
    } else {
        // ---- fused geom3d + pan3d: 2 voxels/thread ----
        int bid3 = blockIdx.x - PAN2_BLOCKS;
        int b = bid3 / (F3D_BLOCKS / B);                 // uniform
        int base = bid3 * 512 + t * 2;                   // index into [B*G3)
        int v = base - b * G3;
        if (t < K) {
            float cy = cyV[b * K + t], cx = cxV[b * K + t];
            cc4[t] = make_float4(-cy, -cy, -cx, -cx);
            cc2[t] = make_float2(-cy, -cx);
            clsL[t] = clA[b * K + t];
        }
        if (t < C) lcnt[t] = 0;
        __syncthreads();
        // issue off3 loads with phase-A loads (latency hidden under argmax)
        const float* ob = off3 + (size_t)b * 3 * G3 + v;
        float2 o0 = *(const float2*)ob;
        float2 o1 = *(const float2*)(ob + G3);
        float2 o2 = *(const float2*)(ob + 2 * (size_t)G3);
        float fx = intr[(size_t)b * 9 + 0];              // uniform (s_load)
        float fy = intr[(size_t)b * 9 + 4];
        float u0 = intr[(size_t)b * 9 + 2];
        float v0 = intr[(size_t)b * 9 + 5];
        // phase A: truncation + 3D argmax + fg class counts
        float2 g = *(const float2*)(geom + base);
        float2 o = *(const float2*)(occ + base);
        float go[2];
        go[0] = (o.x <= 0.0f) ? TRUNCATION : g.x;
        go[1] = (o.y <= 0.0f) ? TRUNCATION : g.y;
        *(float2*)(out + O_GEOM + base) = make_float2(go[0], go[1]);
        const float* s = sem3in + (size_t)b * C * G3 + v;
        float2 s0 = *(const float2*)s;
        float bv[2] = {s0.x, s0.y};
        int bc[2] = {0, 0};
#pragma unroll
        for (int c = 1; c < C; ++c) {
            float2 x = *(const float2*)(s + (size_t)c * G3);
            if (x.x > bv[0]) { bv[0] = x.x; bc[0] = c; }
            if (x.y > bv[1]) { bv[1] = x.y; bc[1] = c; }
        }
        bool fg[2];
        uint8_t sc2[2];
#pragma unroll
        for (int q = 0; q < 2; ++q) {
            fg[q] = fabsf(go[q]) < TSDF_THRESH;
            if (fg[q]) atomicAdd(&lcnt[bc[q]], 1);
            sc2[q] = (fg[q] && bc[q] >= 8) ? (uint8_t)bc[q] : 0;
        }
        *(uchar2*)(stuffCand + base) = make_uchar2(sc2[0], sc2[1]);
        // phase B: projection + group-min argmin (exact FP order)
        int i = v / (G * G);
        int rem = v - i * (G * G);
        int j = rem / G;
        int k0 = rem - j * G;                            // k0, k0+1 same row
        f32x2 vv, uu;
        float oa0[2] = {o0.x, o0.y};
        float oa1[2] = {o1.x, o1.y};
        float oa2[2] = {o2.x, o2.y};
#pragma unroll
        for (int q = 0; q < 2; ++q) {
            float Xm = ((float)i + oa0[q] + 0.5f) * VOXEL_SIZE - HALF_EXT;
            float Ym = ((float)j + oa1[q] + 0.5f) * VOXEL_SIZE - HALF_EXT;
            float Zr = 0.0f + ((float)(k0 + q) + oa2[q] + 0.5f) * VOXEL_SIZE;
            float Zm = fminf(fmaxf(Zr, 0.1f), DEPTH_MAX);
            uu[q] = fx * Xm / Zm + u0;
            vv[q] = fy * Ym / Zm + v0;
        }
        bool anyV = scA[b * K] > CENTER_THRESHOLD;       // uniform
        int bi[2];
        argmin128_p2(cc4, cc2, vv, uu, bi);
        float pout[2];
#pragma unroll
        for (int q = 0; q < 2; ++q) {
            int sem = bc[q];
            int pan = 0;
            if (sem >= 1 && sem <= 7) {        // thing: final value now
                pan = anyV ? (clsL[bi[q]] * LABEL_DIVISOR + bi[q] + 1) : 0;
                if (!fg[q]) pan = 0;
            }                                  // stuff: 0 here, k_stuff fills
            pout[q] = (float)pan;
        }
        *(float2*)(out + O_PAN3 + base) = make_float2(pout[0], pout[1]);
        __syncthreads();
        if (t < C) atomicAdd(&counts3d[b * C + t], lcnt[t]);
    }
}

// Fill stuff voxels (needs completed counts3d). 16 voxels/thread.
__global__ __launch_bounds__(256)
void k_stuff(const uint8_t* __restrict__ stuffCand,
             const int* __restrict__ counts3d,
             float* __restrict__ out) {
    __shared__ int cntL[C];
    constexpr int BPB = F3D_STUFFB / B;                  // 216 blocks per batch
    int t = threadIdx.x;
    int b = blockIdx.x / BPB;                            // uniform
    if (t < C) cntL[t] = counts3d[b * C + t];
    __syncthreads();
    int base = blockIdx.x * 4096 + t * 16;
    uint4 packed = *(const uint4*)(stuffCand + base);
    uint32_t wds[4] = {packed.x, packed.y, packed.z, packed.w};
#pragma unroll
    for (int wq = 0; wq < 4; ++wq) {
        uint32_t wd = wds[wq];
#pragma unroll
        for (int bq = 0; bq < 4; ++bq) {
            int c = (wd >> (8 * bq)) & 0xFF;
            if (c != 0 && cntL[c] >= STUFF_AREA) {
                out[O_PAN3 + base + wq * 4 + bq] = (float)(c * LABEL_DIVISOR);
            }
        }
    }
}

extern "C" void kernel_launch(void* const* d_in, const int* in_sizes, int n_in,
                              void* d_out, int out_size, void* d_ws, size_t ws_size,
                              hipStream_t stream) {
    const float* semantic2d  = (const float*)d_in[0];
    const float* center2d    = (const float*)d_in[1];
    const float* offset2d    = (const float*)d_in[2];
    const float* geometry    = (const float*)d_in[3];
    const float* occupancy3d = (const float*)d_in[4];
    const float* semantic3d  = (const float*)d_in[5];
    const float* offset3d    = (const float*)d_in[6];
    const float* intrinsic   = (const float*)d_in[7];
    float* out = (float*)d_out;
    char* ws = (char*)d_ws;

    int* candCount = (int*)(ws + 0);      // [B]
    int* counts2d  = (int*)(ws + 16);     // [B*C]
    int* counts3d  = (int*)(ws + 112);    // [B*C]
    float* scA = (float*)(ws + WS_SC);
    int*   clA = (int*)(ws + WS_CL);
    uint8_t* semMap  = (uint8_t*)(ws + WS_SEM2);
    uint8_t* nmsMask = (uint8_t*)(ws + WS_NMS);
    float* candVal = (float*)(ws + WS_CV);
    int*   candIdx = (int*)(ws + WS_CI);
    uint8_t* stuffCand = (uint8_t*)(ws + WS_STUF);
    float* cyV = (float*)(ws + WS_CYV);
    float* cxV = (float*)(ws + WS_CXV);

    hipMemsetAsync(d_ws, 0, 256, stream);

    k_pre2d<<<B * (H / 4), 256, 0, stream>>>(semantic2d, center2d, semMap, nmsMask,
                                             candVal, candIdx, candCount, counts2d);
    k_topk<<<B * TOPK_NB, 256, 0, stream>>>(semMap, nmsMask, candVal, candIdx, candCount,
                                            scA, clA, cyV, cxV, out);
    k_fuse<<<PAN2_BLOCKS + F3D_BLOCKS, 256, 0, stream>>>(
        geometry, occupancy3d, semantic3d, stuffCand, counts3d,
        offset2d, semMap, counts2d, offset3d, intrinsic,
        scA, clA, cyV, cxV, out);
    k_stuff<<<F3D_STUFFB, 256, 0, stream>>>(stuffCand, counts3d, out);
}

// Round 16
// 78.615 us; speedup vs baseline: 1.2184x; 1.2184x over previous
//
#include <hip/hip_runtime.h>
#include <stdint.h>

constexpr int B = 2, H = 256, W = 256, G = 96, C = 12, K = 128;
constexpr int HW = H * W;          // 65536
constexpr int G3 = G * G * G;      // 884736
constexpr float CENTER_THRESHOLD = 0.1f;
constexpr int STUFF_AREA = 2048;
constexpr int LABEL_DIVISOR = 1000;
constexpr float VOXEL_SIZE = 0.0625f;
constexpr float TRUNCATION = 3.0f;
constexpr float TSDF_THRESH = 1.5f;
constexpr float DEPTH_MAX = 6.0f;
constexpr float HALF_EXT = 3.0f;   // G*VOXEL_SIZE/2
constexpr int TOPK_CAP = 2048;     // LDS candidate capacity (16 KB; n~1340)
constexpr int TOPK_NB = 64;        // blocks per batch for k_topk
constexpr int PAN2_BLOCKS = (B * HW) / 1024;   // 128
constexpr int F3D_BLOCKS = (B * G3) / 1024;    // 1728

// output layout (floats)
constexpr size_t O_PAN2 = 0;
constexpr size_t O_PAN3 = 131072;
constexpr size_t O_GEOM = 1900544;
constexpr size_t O_CENT = 3670016;
constexpr size_t O_CLS  = 3670528;
constexpr size_t O_SCR  = 3670784;

// ws layout (bytes)
constexpr size_t WS_SC   = 2304;
constexpr size_t WS_CL   = 3328;
constexpr size_t WS_SEM2 = 4352;
constexpr size_t WS_NMS  = 135424;
constexpr size_t WS_CV   = 266496;
constexpr size_t WS_CI   = 790784;
constexpr size_t WS_STUF = 1315072;   // B*G3 bytes (stuff candidate map)
constexpr size_t WS_CYV  = 3084544;
constexpr size_t WS_CXV  = 3085568;

typedef float f32x2 __attribute__((ext_vector_type(2)));

// VOP3P packed fp32: elementwise IEEE-identical to scalar v_add/v_mul.
__device__ inline f32x2 pk_add(f32x2 a, f32x2 b) {
    f32x2 d;
    asm("v_pk_add_f32 %0, %1, %2" : "=v"(d) : "v"(a), "v"(b));
    return d;
}
__device__ inline f32x2 pk_mul(f32x2 a, f32x2 b) {
    f32x2 d;
    asm("v_pk_mul_f32 %0, %1, %2" : "=v"(d) : "v"(a), "v"(b));
    return d;
}

// 4 rows per block, 4 pixels per thread. Separable clamped 7x7 max.
// Candidate emission is block-compacted: LDS staging + ONE global atomic
// per block (R12 win: −16 us vs per-candidate global atomics).
__global__ __launch_bounds__(256)
void k_pre2d(const float* __restrict__ sem2in,
             const float* __restrict__ center2d,
             uint8_t* __restrict__ semMap, uint8_t* __restrict__ nmsMask,
             float* __restrict__ candVal, int* __restrict__ candIdx,
             int* __restrict__ candCount, int* __restrict__ counts2d) {
    __shared__ float vm[4][W];
    __shared__ float lcv[1024];
    __shared__ int   lci[1024];
    __shared__ int lcnt[4];
    __shared__ int cCount;
    __shared__ int gBase;
    int t = threadIdx.x;
    int r = t >> 6;                    // row within block (wave-uniform)
    int c0 = (t & 63) * 4;
    int b = blockIdx.x / (H / 4);
    int h = (blockIdx.x % (H / 4)) * 4 + r;
    if (t < 4) lcnt[t] = 0;
    if (t == 0) cCount = 0;
    const float* hmb = center2d + (size_t)b * HW;
    int h0 = max(h - 3, 0), h1 = min(h + 3, H - 1);
    float4 hm4 = *(const float4*)(hmb + h * W + c0);
    float m0 = -INFINITY, m1 = -INFINITY, m2 = -INFINITY, m3 = -INFINITY;
    for (int y = h0; y <= h1; ++y) {
        float4 v = *(const float4*)(hmb + y * W + c0);
        m0 = fmaxf(m0, v.x); m1 = fmaxf(m1, v.y);
        m2 = fmaxf(m2, v.z); m3 = fmaxf(m3, v.w);
    }
    *(float4*)&vm[r][c0] = make_float4(m0, m1, m2, m3);
    __syncthreads();
    float mm[4];
#pragma unroll
    for (int q = 0; q < 4; ++q) {
        int c = c0 + q;
        int w0 = max(c - 3, 0), w1 = min(c + 3, W - 1);
        float mx = -INFINITY;
        for (int x = w0; x <= w1; ++x) mx = fmaxf(mx, vm[r][x]);
        mm[q] = mx;
    }
    // semantic argmax (first max wins)
    const float* s = sem2in + (size_t)b * C * HW + h * W + c0;
    float4 s0 = *(const float4*)s;
    float bv[4] = {s0.x, s0.y, s0.z, s0.w};
    int cls[4] = {0, 0, 0, 0};
#pragma unroll 4
    for (int c = 1; c < C; ++c) {
        float4 x = *(const float4*)(s + (size_t)c * HW);
        float xa[4] = {x.x, x.y, x.z, x.w};
#pragma unroll
        for (int q = 0; q < 4; ++q)
            if (xa[q] > bv[q]) { bv[q] = xa[q]; cls[q] = c; }
    }
    int p = h * W + c0;
    int gid = b * HW + p;
    *(uchar4*)(semMap + gid) =
        make_uchar4((uint8_t)cls[0], (uint8_t)cls[1], (uint8_t)cls[2], (uint8_t)cls[3]);
    float hma[4] = {hm4.x, hm4.y, hm4.z, hm4.w};
#pragma unroll
    for (int q = 0; q < 4; ++q) {
        if (cls[q] >= 8) atomicAdd(&lcnt[cls[q] - 8], 1);
        bool cand = (hma[q] == mm[q]);
        nmsMask[gid + q] = cand ? 1 : 0;
        if (cand) {
            int pos = atomicAdd(&cCount, 1);   // LDS atomic: cheap
            lcv[pos] = hma[q];
            lci[pos] = p + q;
        }
    }
    __syncthreads();
    if (t == 0) gBase = atomicAdd(&candCount[b], cCount);  // ONE global atomic
    if (t < 4) atomicAdd(&counts2d[b * C + 8 + t], lcnt[t]);
    __syncthreads();
    // coalesced copy-out of the block's candidates
    for (int i = t; i < cCount; i += 256) {
        int pos = gBase + i;
        if (pos < HW) {
            candVal[(size_t)b * HW + pos] = lcv[i];
            candIdx[(size_t)b * HW + pos] = lci[i];
        }
    }
}

// Wave-per-candidate exact top-k (rank scatter; order-invariant).
__global__ __launch_bounds__(256)
void k_topk(const uint8_t* __restrict__ semMap, const uint8_t* __restrict__ nmsMask,
            const float* __restrict__ candVal, const int* __restrict__ candIdx,
            const int* __restrict__ candCount,
            float* __restrict__ scA, int* __restrict__ clA,
            float* __restrict__ cyV, float* __restrict__ cxV,
            float* __restrict__ out) {
    __shared__ float2 cd[TOPK_CAP];
    int b = blockIdx.x / TOPK_NB;
    int sub = blockIdx.x % TOPK_NB;
    int t = threadIdx.x;
    int lane = t & 63;
    int wv = sub * 4 + (t >> 6);
    int n = candCount[b];
    if (n > HW) n = HW;
    const float* cv = candVal + (size_t)b * HW;
    const int*  ci = candIdx + (size_t)b * HW;
    bool useLds = (n <= TOPK_CAP);
    if (useLds) {
        for (int i = t; i < n; i += 256)
            cd[i] = make_float2(cv[i], __int_as_float(ci[i]));
    }
    __syncthreads();
    for (int i = wv; i < n; i += TOPK_NB * 4) {
        float v; int id;
        if (useLds) { float2 c = cd[i]; v = c.x; id = __float_as_int(c.y); }
        else        { v = cv[i]; id = ci[i]; }
        int r = 0;
        if (useLds) {
            for (int j = lane; j < n; j += 64) {
                float2 c = cd[j];
                r += (c.x > v) || (c.x == v && __float_as_int(c.y) < id);
            }
        } else {
            for (int j = lane; j < n; j += 64) {
                float vj = cv[j]; int ij = ci[j];
                r += (vj > v) || (vj == v && ij < id);
            }
        }
#pragma unroll
        for (int off = 32; off >= 1; off >>= 1) r += __shfl_xor(r, off, 64);
        if (lane == 0 && r < K) {
            int o = b * K + r;
            float fy = (float)(id / W);
            float fx = (float)(id % W);
            int cls = (int)semMap[(size_t)b * HW + id];
            bool val = v > CENTER_THRESHOLD;
            scA[o] = v; clA[o] = cls;
            cyV[o] = val ? fy : INFINITY;
            cxV[o] = val ? fx : INFINITY;
            out[O_CENT + (size_t)o * 2 + 0] = fy;
            out[O_CENT + (size_t)o * 2 + 1] = fx;
            out[O_CLS + o] = (float)cls;
            out[O_SCR + o] = v;
        }
    }
    if (sub == 0 && t == 0 && n < K) {
        int r = n;
        for (int p = 0; p < HW && r < K; ++p) {
            if (!nmsMask[(size_t)b * HW + p]) {
                int o = b * K + r;
                float fy = (float)(p / W);
                float fx = (float)(p % W);
                int cls = (int)semMap[(size_t)b * HW + p];
                scA[o] = 0.0f; clA[o] = cls;
                cyV[o] = INFINITY;
                cxV[o] = INFINITY;
                out[O_CENT + (size_t)o * 2 + 0] = fy;
                out[O_CENT + (size_t)o * 2 + 1] = fx;
                out[O_CLS + o] = (float)cls;
                out[O_SCR + o] = 0.0f;
                ++r;
            }
        }
    }
}

// Exact group-min argmin over 128 centers for 4 points held as 2 f32x2 pairs.
// cc4 = (-cy,-cy,-cx,-cx) per center; cc2 = (-cy,-cx).
// Pass 1: per-group (8x16) min chains via pk ops, FULL unroll (benched
// fastest: 16 independent center loads in flight).
// Merge: strict < keeps first group attaining the global min.
// Pass 2: rescan winning group's 16 centers, reverse scan -> first-k-wins.
// All FP ops bit-identical to the scalar reference tree.
__device__ __forceinline__ void argmin128(const float4* __restrict__ cc4,
                                          const float2* __restrict__ cc2,
                                          const f32x2 vv2[2], const f32x2 uu2[2],
                                          int bi[4]) {
#pragma clang fp contract(off)
    f32x2 m0 = {INFINITY, INFINITY}, m1 = {INFINITY, INFINITY};
    int gs[4] = {0, 0, 0, 0};
    for (int g = 0; g < 8; ++g) {
        f32x2 b0 = {INFINITY, INFINITY}, b1 = {INFINITY, INFINITY};
#pragma unroll
        for (int kk = 0; kk < 16; ++kk) {
            float4 c4 = cc4[(g << 4) + kk];
            f32x2 ncy; ncy[0] = c4.x; ncy[1] = c4.y;
            f32x2 ncx; ncx[0] = c4.z; ncx[1] = c4.w;
            f32x2 dv = pk_add(vv2[0], ncy);
            f32x2 du = pk_add(uu2[0], ncx);
            f32x2 d0 = pk_add(pk_mul(dv, dv), pk_mul(du, du));
            dv = pk_add(vv2[1], ncy);
            du = pk_add(uu2[1], ncx);
            f32x2 d1 = pk_add(pk_mul(dv, dv), pk_mul(du, du));
            b0[0] = fminf(b0[0], d0[0]); b0[1] = fminf(b0[1], d0[1]);
            b1[0] = fminf(b1[0], d1[0]); b1[1] = fminf(b1[1], d1[1]);
        }
        if (b0[0] < m0[0]) { m0[0] = b0[0]; gs[0] = g; }
        if (b0[1] < m0[1]) { m0[1] = b0[1]; gs[1] = g; }
        if (b1[0] < m1[0]) { m1[0] = b1[0]; gs[2] = g; }
        if (b1[1] < m1[1]) { m1[1] = b1[1]; gs[3] = g; }
    }
    float vq[4] = {vv2[0][0], vv2[0][1], vv2[1][0], vv2[1][1]};
    float uq[4] = {uu2[0][0], uu2[0][1], uu2[1][0], uu2[1][1]};
    float mq[4] = {m0[0], m0[1], m1[0], m1[1]};
#pragma unroll
    for (int q = 0; q < 4; ++q) {
        int kb = 0;
        int gbase = gs[q] << 4;
#pragma unroll
        for (int kk = 15; kk >= 0; --kk) {
            float2 c2 = cc2[gbase + kk];
            float dv = vq[q] + c2.x;
            float du = uq[q] + c2.y;
            float d = dv * dv + du * du;
            if (d == mq[q]) kb = kk;        // last write = smallest kk
        }
        bi[q] = gbase + kb;
    }
}

// Fused: pan2d blocks [0,PAN2_BLOCKS) + {geom3d+pan3d} blocks (rest).
// Plain launch_bounds(256): empirical gfx950 rule — (256,N) caps VGPR at
// ~256/N; this kernel compiles to ~84 VGPR and capping below spills
// (R7: +2.6x HBM; R9: +50% HBM). 4 voxels/thread is the measured optimum
// (8/thr=62us R3, 2/thr regressed R14). off3 loads issued with phase-A
// loads so their latency hides under the argmax chain.
__global__ __launch_bounds__(256)
void k_fuse(const float* __restrict__ geom, const float* __restrict__ occ,
            const float* __restrict__ sem3in,
            uint8_t* __restrict__ stuffCand, int* __restrict__ counts3d,
            const float* __restrict__ offset2d,
            const uint8_t* __restrict__ semMap,
            const int* __restrict__ counts2d,
            const float* __restrict__ off3,
            const float* __restrict__ intr,
            const float* __restrict__ scA, const int* __restrict__ clA,
            const float* __restrict__ cyV, const float* __restrict__ cxV,
            float* __restrict__ out) {
#pragma clang fp contract(off)
    __shared__ float4 cc4[K];
    __shared__ float2 cc2[K];
    __shared__ int clsL[K];
    __shared__ int lcnt[C];
    __shared__ int cntL[C];
    int t = threadIdx.x;
    if (blockIdx.x < PAN2_BLOCKS) {
        // ---- pan2d: 4 pixels/thread ----
        int b = blockIdx.x / (PAN2_BLOCKS / B);          // uniform
        int base = blockIdx.x * 1024 + t * 4;
        int p = base - b * HW;
        if (t < K) {
            float cy = cyV[b * K + t], cx = cxV[b * K + t];
            cc4[t] = make_float4(-cy, -cy, -cx, -cx);
            cc2[t] = make_float2(-cy, -cx);
            clsL[t] = clA[b * K + t];
        }
        if (t < C) cntL[t] = counts2d[b * C + t];
        __syncthreads();
        bool anyV = scA[b * K] > CENTER_THRESHOLD;       // uniform
        int h = p / W, w = p % W;
        const float* offb = offset2d + (size_t)b * 2 * HW + p;
        float4 oy = *(const float4*)offb;
        float4 ox = *(const float4*)(offb + HW);
        f32x2 py2[2], px2[2];
        py2[0][0] = (float)h + oy.x;        py2[0][1] = (float)h + oy.y;
        py2[1][0] = (float)h + oy.z;        py2[1][1] = (float)h + oy.w;
        px2[0][0] = (float)(w + 0) + ox.x;  px2[0][1] = (float)(w + 1) + ox.y;
        px2[1][0] = (float)(w + 2) + ox.z;  px2[1][1] = (float)(w + 3) + ox.w;
        int bi[4];
        argmin128(cc4, cc2, py2, px2, bi);
        uchar4 s4 = *(const uchar4*)(semMap + base);
        int sa[4] = {s4.x, s4.y, s4.z, s4.w};
        float pout[4];
#pragma unroll
        for (int q = 0; q < 4; ++q) {
            int sem = sa[q];
            int pan;
            if (sem >= 1 && sem <= 7) {
                pan = anyV ? (clsL[bi[q]] * LABEL_DIVISOR + bi[q] + 1) : 0;
            } else {
                pan = (cntL[sem] >= STUFF_AREA) ? sem * LABEL_DIVISOR : 0;
            }
            pout[q] = (float)pan;
        }
        *(float4*)(out + O_PAN2 + base) = make_float4(pout[0], pout[1], pout[2], pout[3]);
    } else {
        // ---- fused geom3d + pan3d: 4 voxels/thread ----
        int bid3 = blockIdx.x - PAN2_BLOCKS;
        int b = bid3 / (F3D_BLOCKS / B);                 // uniform
        int base = bid3 * 1024 + t * 4;                  // index into [B*G3)
        int v = base - b * G3;
        if (t < K) {
            float cy = cyV[b * K + t], cx = cxV[b * K + t];
            cc4[t] = make_float4(-cy, -cy, -cx, -cx);
            cc2[t] = make_float2(-cy, -cx);
            clsL[t] = clA[b * K + t];
        }
        if (t < C) lcnt[t] = 0;
        __syncthreads();
        // Issue ALL global loads up-front: off3 (phase B) together with
        // geom/occ/sem (phase A) — argmax chain hides off3 latency.
        const float* ob = off3 + (size_t)b * 3 * G3 + v;
        float4 o0 = *(const float4*)ob;
        float4 o1 = *(const float4*)(ob + G3);
        float4 o2 = *(const float4*)(ob + 2 * (size_t)G3);
        float fx = intr[(size_t)b * 9 + 0];              // uniform (s_load)
        float fy = intr[(size_t)b * 9 + 4];
        float u0 = intr[(size_t)b * 9 + 2];
        float v0 = intr[(size_t)b * 9 + 5];
        // phase A: truncation + 3D argmax + fg class counts
        float4 g = *(const float4*)(geom + base);
        float4 o = *(const float4*)(occ + base);
        float go[4];
        go[0] = (o.x <= 0.0f) ? TRUNCATION : g.x;
        go[1] = (o.y <= 0.0f) ? TRUNCATION : g.y;
        go[2] = (o.z <= 0.0f) ? TRUNCATION : g.z;
        go[3] = (o.w <= 0.0f) ? TRUNCATION : g.w;
        *(float4*)(out + O_GEOM + base) = make_float4(go[0], go[1], go[2], go[3]);
        const float* s = sem3in + (size_t)b * C * G3 + v;
        float4 s0 = *(const float4*)s;
        float bv[4] = {s0.x, s0.y, s0.z, s0.w};
        int bc[4] = {0, 0, 0, 0};
#pragma unroll
        for (int c = 1; c < C; ++c) {
            float4 x = *(const float4*)(s + (size_t)c * G3);
            float xa[4] = {x.x, x.y, x.z, x.w};
#pragma unroll
            for (int q = 0; q < 4; ++q)
                if (xa[q] > bv[q]) { bv[q] = xa[q]; bc[q] = c; }
        }
        bool fg[4];
        uint8_t sc4[4];
#pragma unroll
        for (int q = 0; q < 4; ++q) {
            fg[q] = fabsf(go[q]) < TSDF_THRESH;
            if (fg[q]) atomicAdd(&lcnt[bc[q]], 1);
            sc4[q] = (fg[q] && bc[q] >= 8) ? (uint8_t)bc[q] : 0;
        }
        *(uchar4*)(stuffCand + base) = make_uchar4(sc4[0], sc4[1], sc4[2], sc4[3]);
        // phase B: projection + group-min argmin (exact FP order)
        int i = v / (G * G);
        int rem = v - i * (G * G);
        int j = rem / G;
        int k0 = rem - j * G;                            // k0..k0+3 same row
        float oa0[4] = {o0.x, o0.y, o0.z, o0.w};
        float oa1[4] = {o1.x, o1.y, o1.z, o1.w};
        float oa2[4] = {o2.x, o2.y, o2.z, o2.w};
        f32x2 vv2[2], uu2[2];
#pragma unroll
        for (int q = 0; q < 4; ++q) {
            float Xm = ((float)i + oa0[q] + 0.5f) * VOXEL_SIZE - HALF_EXT;
            float Ym = ((float)j + oa1[q] + 0.5f) * VOXEL_SIZE - HALF_EXT;
            float Zr = 0.0f + ((float)(k0 + q) + oa2[q] + 0.5f) * VOXEL_SIZE;
            float Zm = fminf(fmaxf(Zr, 0.1f), DEPTH_MAX);
            uu2[q >> 1][q & 1] = fx * Xm / Zm + u0;
            vv2[q >> 1][q & 1] = fy * Ym / Zm + v0;
        }
        bool anyV = scA[b * K] > CENTER_THRESHOLD;       // uniform
        int bi[4];
        argmin128(cc4, cc2, vv2, uu2, bi);
        float pout[4];
#pragma unroll
        for (int q = 0; q < 4; ++q) {
            int sem = bc[q];
            int pan = 0;
            if (sem >= 1 && sem <= 7) {        // thing: final value now
                pan = anyV ? (clsL[bi[q]] * LABEL_DIVISOR + bi[q] + 1) : 0;
                if (!fg[q]) pan = 0;
            }                                  // stuff: 0 here, k_stuff fills
            pout[q] = (float)pan;
        }
        *(float4*)(out + O_PAN3 + base) = make_float4(pout[0], pout[1], pout[2], pout[3]);
        __syncthreads();
        if (t < C) atomicAdd(&counts3d[b * C + t], lcnt[t]);
    }
}

// Fill stuff voxels (needs completed counts3d). 16 voxels/thread.
__global__ __launch_bounds__(256)
void k_stuff(const uint8_t* __restrict__ stuffCand,
             const int* __restrict__ counts3d,
             float* __restrict__ out) {
    __shared__ int cntL[C];
    constexpr int BPB = F3D_BLOCKS / 4 / B;              // 216 blocks per batch
    int t = threadIdx.x;
    int b = blockIdx.x / BPB;                            // uniform
    if (t < C) cntL[t] = counts3d[b * C + t];
    __syncthreads();
    int base = blockIdx.x * 4096 + t * 16;
    uint4 packed = *(const uint4*)(stuffCand + base);
    uint32_t wds[4] = {packed.x, packed.y, packed.z, packed.w};
#pragma unroll
    for (int wq = 0; wq < 4; ++wq) {
        uint32_t wd = wds[wq];
#pragma unroll
        for (int bq = 0; bq < 4; ++bq) {
            int c = (wd >> (8 * bq)) & 0xFF;
            if (c != 0 && cntL[c] >= STUFF_AREA) {
                out[O_PAN3 + base + wq * 4 + bq] = (float)(c * LABEL_DIVISOR);
            }
        }
    }
}

extern "C" void kernel_launch(void* const* d_in, const int* in_sizes, int n_in,
                              void* d_out, int out_size, void* d_ws, size_t ws_size,
                              hipStream_t stream) {
    const float* semantic2d  = (const float*)d_in[0];
    const float* center2d    = (const float*)d_in[1];
    const float* offset2d    = (const float*)d_in[2];
    const float* geometry    = (const float*)d_in[3];
    const float* occupancy3d = (const float*)d_in[4];
    const float* semantic3d  = (const float*)d_in[5];
    const float* offset3d    = (const float*)d_in[6];
    const float* intrinsic   = (const float*)d_in[7];
    float* out = (float*)d_out;
    char* ws = (char*)d_ws;

    int* candCount = (int*)(ws + 0);      // [B]
    int* counts2d  = (int*)(ws + 16);     // [B*C]
    int* counts3d  = (int*)(ws + 112);    // [B*C]
    float* scA = (float*)(ws + WS_SC);
    int*   clA = (int*)(ws + WS_CL);
    uint8_t* semMap  = (uint8_t*)(ws + WS_SEM2);
    uint8_t* nmsMask = (uint8_t*)(ws + WS_NMS);
    float* candVal = (float*)(ws + WS_CV);
    int*   candIdx = (int*)(ws + WS_CI);
    uint8_t* stuffCand = (uint8_t*)(ws + WS_STUF);
    float* cyV = (float*)(ws + WS_CYV);
    float* cxV = (float*)(ws + WS_CXV);

    hipMemsetAsync(d_ws, 0, 256, stream);

    k_pre2d<<<B * (H / 4), 256, 0, stream>>>(semantic2d, center2d, semMap, nmsMask,
                                             candVal, candIdx, candCount, counts2d);
    k_topk<<<B * TOPK_NB, 256, 0, stream>>>(semMap, nmsMask, candVal, candIdx, candCount,
                                            scA, clA, cyV, cxV, out);
    k_fuse<<<PAN2_BLOCKS + F3D_BLOCKS, 256, 0, stream>>>(
        geometry, occupancy3d, semantic3d, stuffCand, counts3d,
        offset2d, semMap, counts2d, offset3d, intrinsic,
        scA, clA, cyV, cxV, out);
    k_stuff<<<F3D_BLOCKS / 4, 256, 0, stream>>>(stuffCand, counts3d, out);
}